// Round 1
// baseline (462.923 us; speedup 1.0000x reference)
//
#include <hip/hip_runtime.h>
#include <cstdint>

typedef unsigned short u16;
typedef short s16x8 __attribute__((ext_vector_type(8)));
typedef float f32x4 __attribute__((ext_vector_type(4)));

__device__ __forceinline__ u16 f2bf(float x) {
  uint32_t u = __builtin_bit_cast(uint32_t, x);
  u += 0x7FFFu + ((u >> 16) & 1u);   // round-to-nearest-even
  return (u16)(u >> 16);
}
__device__ __forceinline__ float bf2f(u16 v) {
  return __builtin_bit_cast(float, (uint32_t)v << 16);
}
__device__ __forceinline__ f32x4 mfma16(s16x8 a, s16x8 b, f32x4 c) {
  return __builtin_amdgcn_mfma_f32_16x16x32_bf16(a, b, c, 0, 0, 0);
}
__device__ __forceinline__ s16x8 ld_frag(const u16* p) {
  uint4 v = *(const uint4*)p;
  return __builtin_bit_cast(s16x8, v);
}

// ---------------- kernel 1: weights fp32 -> bf16 (scale folded into Wq) ----
__global__ void prep_w(const float* __restrict__ Wq, const float* __restrict__ Wkv,
                       u16* __restrict__ wqb, u16* __restrict__ wkvb) {
  int i = blockIdx.x * 256 + threadIdx.x;          // grid 288*256 = 73728
  const float scale = 0.17677669529663687f;        // 1/sqrt(32)
  if (i < 36864) wqb[i] = f2bf(Wq[i] * scale);
  wkvb[i] = f2bf(Wkv[i]);
}

// ---------------- kernel 2: rpb[h][n][q] = bf16(table[rpi[q][n]][h]) -------
__global__ void build_rpb(const int* __restrict__ rpi, const float* __restrict__ table,
                          u16* __restrict__ rpb) {
  __shared__ int tile[64][65];                     // [n][q], +1 pad
  const int q0 = blockIdx.x << 6, n0 = blockIdx.y << 6;
  for (int i = threadIdx.x; i < 4096; i += 256) {  // coalesced rpi reads
    int q = i >> 6, n = i & 63;
    tile[n][q] = rpi[(size_t)(q0 + q) * 576 + n0 + n];
  }
  __syncthreads();
  for (int i = threadIdx.x; i < 4096; i += 256) {  // coalesced rpb writes (q fastest)
    int n = i >> 6, q = i & 63;
    int idx = tile[n][q] * 6;
#pragma unroll
    for (int h = 0; h < 6; ++h)
      rpb[((size_t)(h * 576 + n0 + n) << 8) + q0 + q] = f2bf(table[idx + h]);
  }
}

// ---------------- kernels 3/4: projection GEMM -----------------------------
// C[m][f] = A[m][0:192] . Wb[f][0:192]; A fp32, Wb bf16 row-major.
// mode 0: out Qws[b][h][q][32]   (M = 65536, nchunks = 3)
// mode 1: out K/V ws[b][h][tok][32] (M = 147456, nchunks = 6)
__launch_bounds__(256, 3)
__global__ void proj_gemm(const float* __restrict__ A, const u16* __restrict__ Wb,
                          u16* __restrict__ outQ, u16* __restrict__ outK,
                          u16* __restrict__ outV, int nchunks, int mode) {
  __shared__ __align__(16) u16 As[128 * 200];      // 128 rows x 192 + 8 pad
  const int m0 = blockIdx.x << 7;
  const int t = threadIdx.x;
#pragma unroll
  for (int i = 0; i < 24; ++i) {                   // stage A tile fp32->bf16
    int idx = t + (i << 8);
    int r = idx / 48, cc = idx - r * 48;
    float4 v = ((const float4*)(A + (size_t)(m0 + r) * 192))[cc];
    union { uint2 u; u16 s[4]; } pk;
    pk.s[0] = f2bf(v.x); pk.s[1] = f2bf(v.y); pk.s[2] = f2bf(v.z); pk.s[3] = f2bf(v.w);
    *(uint2*)(&As[r * 200 + (cc << 2)]) = pk.u;
  }
  __syncthreads();
  const int w = t >> 6, lane = t & 63, c = lane & 15, hi = lane >> 4;
  s16x8 af[2][6];                                  // hoist A-frags across N-chunks
#pragma unroll
  for (int mb = 0; mb < 2; ++mb) {
    int row = (w << 5) + (mb << 4) + c;
#pragma unroll
    for (int k = 0; k < 6; ++k)
      af[mb][k] = ld_frag(&As[row * 200 + (k << 5) + (hi << 3)]);
  }
  for (int nc = 0; nc < nchunks; ++nc) {
    f32x4 acc[2][4];
#pragma unroll
    for (int mb = 0; mb < 2; ++mb)
#pragma unroll
      for (int nb = 0; nb < 4; ++nb) acc[mb][nb] = f32x4{0.f, 0.f, 0.f, 0.f};
#pragma unroll
    for (int k = 0; k < 6; ++k) {
#pragma unroll
      for (int nb = 0; nb < 4; ++nb) {
        int f = (nc << 6) + (nb << 4) + c;
        s16x8 bf = ld_frag(&Wb[(size_t)f * 192 + (k << 5) + (hi << 3)]);
        acc[0][nb] = mfma16(af[0][k], bf, acc[0][nb]);
        acc[1][nb] = mfma16(af[1][k], bf, acc[1][nb]);
      }
    }
#pragma unroll
    for (int mb = 0; mb < 2; ++mb)
#pragma unroll
      for (int nb = 0; nb < 4; ++nb) {
        int f = (nc << 6) + (nb << 4) + c;
#pragma unroll
        for (int r = 0; r < 4; ++r) {
          int m = m0 + (w << 5) + (mb << 4) + (hi << 2) + r;
          u16 bv = f2bf(acc[mb][nb][r]);
          if (mode == 0) {
            int b = m >> 8, q = m & 255, h = f >> 5, d = f & 31;
            outQ[((((size_t)(b * 6 + h)) << 8) + q) * 32 + d] = bv;
          } else {
            int b = m / 576, tok = m - b * 576;
            int f2 = f; u16* dst = outK;
            if (f2 >= 192) { dst = outV; f2 -= 192; }
            int h = f2 >> 5, d = f2 & 31;
            dst[(((size_t)(b * 6 + h)) * 576 + tok) * 32 + d] = bv;
          }
        }
      }
  }
}

// ---------------- kernel 5: fused attention per (b,h) ----------------------
// 8 waves x 32 q-rows. Unnormalized exp (logits are O(0.5), no max needed),
// row-sum + divide at the end. P: MFMA C-layout -> A-layout via per-wave LDS.
__launch_bounds__(512, 4)
__global__ void attn(const u16* __restrict__ Qws, const u16* __restrict__ Kws,
                     const u16* __restrict__ Vws, const u16* __restrict__ rpb,
                     float* __restrict__ out) {
  __shared__ __align__(16) u16 Vt[32 * 584];       // V transposed [d][key], pad->2-way free
  __shared__ __align__(16) u16 Ps[8][32 * 40];     // per-wave P tile, stride 40
  const int bh = blockIdx.x, b = bh / 6, h = bh - b * 6;
  const size_t kvbase = (size_t)bh * 576 * 32;
  const int t = threadIdx.x;
  for (int i = t; i < 2304; i += 512) {            // stage V transposed
    int key = i >> 2, dblk = i & 3;
    union { uint4 u; u16 s[8]; } v;
    v.u = *(const uint4*)(&Vws[kvbase + key * 32 + (dblk << 3)]);
#pragma unroll
    for (int j = 0; j < 8; ++j) Vt[((dblk << 3) + j) * 584 + key] = v.s[j];
  }
  const int w = t >> 6, lane = t & 63, c = lane & 15, hi = lane >> 4;
  const int q0 = w << 5;
  s16x8 qf[2];                                     // Q frags: registers for whole kernel
#pragma unroll
  for (int mb = 0; mb < 2; ++mb)
    qf[mb] = ld_frag(&Qws[((size_t)bh * 256 + q0 + (mb << 4) + c) * 32 + (hi << 3)]);
  __syncthreads();
  f32x4 oacc[2][2];
  float ps[2][4];
#pragma unroll
  for (int mb = 0; mb < 2; ++mb) {
#pragma unroll
    for (int db = 0; db < 2; ++db) oacc[mb][db] = f32x4{0.f, 0.f, 0.f, 0.f};
#pragma unroll
    for (int r = 0; r < 4; ++r) ps[mb][r] = 0.f;
  }
  u16* myPs = &Ps[w][0];
  const u16* rpbh = rpb + (size_t)h * 576 * 256;
  for (int kt = 0; kt < 18; ++kt) {
    const int k0 = kt << 5;
    s16x8 kf0 = ld_frag(&Kws[kvbase + (size_t)(k0 + c) * 32 + (hi << 3)]);
    s16x8 kf1 = ld_frag(&Kws[kvbase + (size_t)(k0 + 16 + c) * 32 + (hi << 3)]);
    ushort4 bb[2][2];
#pragma unroll
    for (int mb = 0; mb < 2; ++mb)
#pragma unroll
      for (int nb = 0; nb < 2; ++nb)
        bb[mb][nb] = *(const ushort4*)(
            &rpbh[((size_t)(k0 + (nb << 4) + c) << 8) + q0 + (mb << 4) + (hi << 2)]);
    f32x4 s[2][2];
#pragma unroll
    for (int mb = 0; mb < 2; ++mb)
#pragma unroll
      for (int nb = 0; nb < 2; ++nb) s[mb][nb] = f32x4{0.f, 0.f, 0.f, 0.f};
    s[0][0] = mfma16(qf[0], kf0, s[0][0]);
    s[0][1] = mfma16(qf[0], kf1, s[0][1]);
    s[1][0] = mfma16(qf[1], kf0, s[1][0]);
    s[1][1] = mfma16(qf[1], kf1, s[1][1]);
#pragma unroll
    for (int mb = 0; mb < 2; ++mb)
#pragma unroll
      for (int nb = 0; nb < 2; ++nb) {
        const u16* bp = (const u16*)&bb[mb][nb];
#pragma unroll
        for (int r = 0; r < 4; ++r) {
          float p = __expf(s[mb][nb][r] + bf2f(bp[r]));
          ps[mb][r] += p;
          myPs[((mb << 4) + (hi << 2) + r) * 40 + (nb << 4) + c] = f2bf(p);
        }
      }
    // intra-wave cross-lane LDS dependency: drain DS queue before re-reading
    __asm__ volatile("s_waitcnt lgkmcnt(0)" ::: "memory");
    s16x8 pf0 = ld_frag(&myPs[c * 40 + (hi << 3)]);
    s16x8 pf1 = ld_frag(&myPs[(16 + c) * 40 + (hi << 3)]);
#pragma unroll
    for (int db = 0; db < 2; ++db) {
      s16x8 vf = ld_frag(&Vt[((db << 4) + c) * 584 + k0 + (hi << 3)]);
      oacc[0][db] = mfma16(pf0, vf, oacc[0][db]);
      oacc[1][db] = mfma16(pf1, vf, oacc[1][db]);
    }
  }
#pragma unroll
  for (int mb = 0; mb < 2; ++mb)
#pragma unroll
    for (int r = 0; r < 4; ++r) {                  // row-sum across the 16 col-lanes
      float v = ps[mb][r];
      v += __shfl_xor(v, 1);
      v += __shfl_xor(v, 2);
      v += __shfl_xor(v, 4);
      v += __shfl_xor(v, 8);
      ps[mb][r] = 1.0f / v;
    }
  float* ob = out + (size_t)b * 256 * 192 + h * 32;
#pragma unroll
  for (int mb = 0; mb < 2; ++mb)
#pragma unroll
    for (int r = 0; r < 4; ++r) {
      int q = q0 + (mb << 4) + (hi << 2) + r;
#pragma unroll
      for (int db = 0; db < 2; ++db)
        ob[(size_t)q * 192 + (db << 4) + c] = oacc[mb][db][r] * ps[mb][r];
    }
}

// ---------------- launcher -------------------------------------------------
extern "C" void kernel_launch(void* const* d_in, const int* in_sizes, int n_in,
                              void* d_out, int out_size, void* d_ws, size_t ws_size,
                              hipStream_t stream) {
  const float* x_q   = (const float*)d_in[0];
  const float* x_kv  = (const float*)d_in[1];
  const int*   rpi   = (const int*)d_in[2];
  const float* Wq    = (const float*)d_in[3];
  const float* Wkv   = (const float*)d_in[4];
  const float* table = (const float*)d_in[5];
  float* out = (float*)d_out;

  char* ws = (char*)d_ws;
  u16* wqb  = (u16*)(ws);                          //    73,728 B
  u16* wkvb = (u16*)(ws + 73728);                  //   147,456 B
  u16* rpb  = (u16*)(ws + 221184);                 // 1,769,472 B
  u16* Qws  = (u16*)(ws + 1990656);                // 25,165,824 B
  u16* Kws  = (u16*)(ws + 27156480);               // 56,623,104 B
  u16* Vws  = (u16*)(ws + 83779584);               // 56,623,104 B  (total ~134 MB)

  prep_w<<<288, 256, 0, stream>>>(Wq, Wkv, wqb, wkvb);
  build_rpb<<<dim3(4, 9), 256, 0, stream>>>(rpi, table, rpb);
  proj_gemm<<<512, 256, 0, stream>>>(x_q, wqb, Qws, nullptr, nullptr, 3, 0);
  proj_gemm<<<1152, 256, 0, stream>>>(x_kv, wkvb, nullptr, Kws, Vws, 6, 1);
  attn<<<1536, 512, 0, stream>>>(Qws, Kws, Vws, rpb, out);
}